// Round 8
// baseline (556.145 us; speedup 1.0000x reference)
//
#include <hip/hip_runtime.h>
#include <hip/hip_fp16.h>
#include <hip/hip_cooperative_groups.h>

namespace cg = cooperative_groups;

#define FH 240
#define FW 240
#define NSAMP 179   // 9 + 49 + 121
constexpr float IMG = 960.0f;

// ---------------- ws layout (floats) ----------------
static constexpr int WS_FMT   = 0;        // fmT fp16 [240][240][64] -> 1,843,200 float slots
static constexpr int WS_GPART = 1843200;  // gpartial [960][64]
static constexpr int WS_G     = 1904640;  // g [64] (pre-scaled by 1/57600)
static constexpr int WS_PERM  = 1904704;  // perm [4000] ints

// scratch region (bytes): max(transpose 16640, sort 2048, pool 31104, mlp 49664)
static constexpr int SCR_BYTES = 49664;

__device__ __forceinline__ void acc8(float* a, const __half* __restrict__ base,
                                     int off, int c8, float w) {
    float4 raw = *(const float4*)(base + off + c8);   // 8 fp16
    const __half2* h = (const __half2*)&raw;
    #pragma unroll
    for (int i = 0; i < 4; ++i) {
        float2 f = __half22float2(h[i]);
        a[2*i]     = fmaf(w, f.x, a[2*i]);
        a[2*i + 1] = fmaf(w, f.y, a[2*i + 1]);
    }
}

__global__ __launch_bounds__(256, 2) void k_fused(
    const float* __restrict__ fm, __half* __restrict__ fmT,
    float* __restrict__ gpartial, float* __restrict__ g,
    const float* __restrict__ boxes, int* __restrict__ perm,
    const float* __restrict__ W1, const float* __restrict__ b1,
    const float* __restrict__ W2, const float* __restrict__ b2,
    const float* __restrict__ P1, const float* __restrict__ bp1,
    const float* __restrict__ P2, const float* __restrict__ bp2,
    float* __restrict__ out, int n)
{
    __shared__ float pooled_s[8][192];               // persists pool -> mlp
    __shared__ __align__(16) char scr[SCR_BYTES];    // phase-overlaid scratch
    int tid = threadIdx.x;
    int bid = blockIdx.x;
    int nblk = gridDim.x;
    cg::grid_group gg = cg::this_grid();

    // ================= Phase A: transpose fm -> fp16 fmT + per-tile channel sums =================
    {
        float (*tile)[65] = (float(*)[65])scr;
        for (int t = bid; t < 960; t += nblk) {
            int y = t >> 2, x0 = (t & 3) * 64;
            int lane = tid & 63, wv = tid >> 6;
            int x = x0 + lane;
            bool xin = (x < FW);
            #pragma unroll
            for (int k = 0; k < 16; ++k) {
                int c = wv + k * 4;
                tile[c][lane] = xin ? fm[c * (FH * FW) + y * FW + x] : 0.0f;
            }
            __syncthreads();
            if (tid < 64) {
                float s = 0.0f;
                #pragma unroll
                for (int i = 0; i < 64; ++i) s += tile[tid][i];
                gpartial[t * 64 + tid] = s;
            }
            #pragma unroll
            for (int it = 0; it < 2; ++it) {
                int idx = tid + it * 256;       // 0..511
                int xl  = idx >> 3;             // 0..63
                int co  = (idx & 7) * 8;        // 0,8,...,56
                int xx  = x0 + xl;
                if (xx < FW) {
                    union { float4 f4; __half2 h2[4]; } u;
                    #pragma unroll
                    for (int i = 0; i < 4; ++i)
                        u.h2[i] = __floats2half2_rn(tile[co + 2*i][xl], tile[co + 2*i + 1][xl]);
                    *(float4*)&fmT[((size_t)(y * FW + xx)) * 64 + co] = u.f4;
                }
            }
            __syncthreads();
        }
    }
    // ---- counting sort of boxes by (cy,cx) 16x16 buckets: last block ----
    if (bid == nblk - 1) {
        int* hist = (int*)scr;
        int* offs = hist + 256;
        hist[tid] = 0;
        __syncthreads();
        for (int i = tid; i < n; i += 256) {
            float cy = (boxes[i * 4 + 1] + boxes[i * 4 + 3]) * 0.5f;
            float cx = (boxes[i * 4 + 0] + boxes[i * 4 + 2]) * 0.5f;
            int by = min(15, max(0, (int)(cy * (16.0f / 960.0f))));
            int bx = min(15, max(0, (int)(cx * (16.0f / 960.0f))));
            atomicAdd(&hist[by * 16 + bx], 1);
        }
        __syncthreads();
        offs[tid] = hist[tid];
        __syncthreads();
        for (int st = 1; st < 256; st <<= 1) {
            int t2 = (tid >= st) ? offs[tid - st] : 0;
            __syncthreads();
            offs[tid] += t2;
            __syncthreads();
        }
        hist[tid] = offs[tid] - hist[tid];     // exclusive start per bucket
        __syncthreads();
        for (int i = tid; i < n; i += 256) {
            float cy = (boxes[i * 4 + 1] + boxes[i * 4 + 3]) * 0.5f;
            float cx = (boxes[i * 4 + 0] + boxes[i * 4 + 2]) * 0.5f;
            int by = min(15, max(0, (int)(cy * (16.0f / 960.0f))));
            int bx = min(15, max(0, (int)(cx * (16.0f / 960.0f))));
            int pos = atomicAdd(&hist[by * 16 + bx], 1);
            perm[pos] = i;
        }
    }
    gg.sync();

    // ================= Phase B: block 0 reduces gpartial -> g =================
    if (bid == 0) {
        float* red = (float*)scr;
        int c = tid & 63, q = tid >> 6;
        float s = 0.0f;
        for (int i = q * 240; i < q * 240 + 240; ++i) s += gpartial[i * 64 + c];
        red[tid] = s;
        __syncthreads();
        if (tid < 64)
            g[tid] = (red[tid] + red[64 + tid] + red[128 + tid] + red[192 + tid]) * (1.0f / 57600.0f);
    }
    gg.sync();

    // ================= Phase C: per block: pool 8 boxes (LDS) + MLP =================
    int ngroups = (n + 7) >> 3;
    const int start_[3] = {0, 9, 58};
    const int end_[3]   = {9, 58, NSAMP};

    for (int grp = bid; grp < ngroups; grp += nblk) {
        int base = grp * 8;
        int* smp    = (int*)scr;                    // NSAMP*8 ints = 5728 B
        float* part = (float*)(scr + 5760);         // 3*64*33 floats = 25344 B

        // software-pipelined: phase1(r) co-scheduled with reduce(r-1)
        for (int r = 0; r <= 8; ++r) {
            if (r < 8 && tid < NSAMP && base + r < n) {
                int box = perm[base + r];
                float bx1 = boxes[box * 4 + 0], by1 = boxes[box * 4 + 1];
                float bx2 = boxes[box * 4 + 2], by2 = boxes[box * 4 + 3];
                float x1n = (bx1 / IMG) * 2.0f - 1.0f;
                float y1n = (by1 / IMG) * 2.0f - 1.0f;
                float x2n = (bx2 / IMG) * 2.0f - 1.0f;
                float y2n = (by2 / IMG) * 2.0f - 1.0f;
                float cx = (x1n + x2n) * 0.5f, cy = (y1n + y2n) * 0.5f;
                float w2 = fmaxf(x2n - x1n, 1e-6f) * 0.5f;
                float h2 = fmaxf(y2n - y1n, 1e-6f) * 0.5f;
                int S, s;
                if (tid < 9)       { S = 3;  s = tid; }
                else if (tid < 58) { S = 7;  s = tid - 9; }
                else               { S = 11; s = tid - 58; }
                int i = s / S;
                int j = s - i * S;
                float Sf = (float)S;
                float bj = (2.0f * (float)j + 1.0f) / Sf - 1.0f;
                float bi = (2.0f * (float)i + 1.0f) / Sf - 1.0f;
                float gx = w2 * bj + cx;
                float gy = h2 * bi + cy;
                float ix = ((gx + 1.0f) * 240.0f - 1.0f) * 0.5f;
                float iy = ((gy + 1.0f) * 240.0f - 1.0f) * 0.5f;
                float x0f = floorf(ix), y0f = floorf(iy);
                float dx = ix - x0f,    dy = iy - y0f;
                int x0 = (int)x0f, y0 = (int)y0f;
                int x1 = x0 + 1,   y1 = y0 + 1;
                float inv = 1.0f / (Sf * Sf);
                float wx0 = (x0 >= 0 && x0 < FW) ? (1.0f - dx) : 0.0f;
                float wx1 = (x1 >= 0 && x1 < FW) ? dx          : 0.0f;
                float wy0 = (y0 >= 0 && y0 < FH) ? (1.0f - dy) : 0.0f;
                float wy1 = (y1 >= 0 && y1 < FH) ? dy          : 0.0f;
                int x0c = min(max(x0, 0), FW - 1), x1c = min(max(x1, 0), FW - 1);
                int y0c = min(max(y0, 0), FH - 1), y1c = min(max(y1, 0), FH - 1);
                int r0 = y0c * FW, r1 = y1c * FW;
                smp[tid * 8 + 0] = (r0 + x0c) * 64;
                smp[tid * 8 + 1] = (r0 + x1c) * 64;
                smp[tid * 8 + 2] = (r1 + x0c) * 64;
                smp[tid * 8 + 3] = (r1 + x1c) * 64;
                float* wp = (float*)&smp[tid * 8 + 4];
                wp[0] = wx0 * wy0 * inv;
                wp[1] = wx1 * wy0 * inv;
                wp[2] = wx0 * wy1 * inv;
                wp[3] = wx1 * wy1 * inv;
            }
            if (r > 0 && tid < 192) {
                int sc = tid >> 6, c = tid & 63;
                float sum = 0.0f;
                #pragma unroll
                for (int q = 0; q < 32; ++q) sum += part[sc * 2112 + c * 33 + q];
                pooled_s[r - 1][tid] = sum;
            }
            __syncthreads();
            if (r < 8 && base + r < n) {
                int slot = tid >> 3, l = tid & 7, c8 = l << 3;
                float a[3][8];
                #pragma unroll
                for (int sc = 0; sc < 3; ++sc)
                    #pragma unroll
                    for (int k = 0; k < 8; ++k) a[sc][k] = 0.0f;
                #pragma unroll
                for (int sc = 0; sc < 3; ++sc) {
                    for (int s = start_[sc] + slot; s < end_[sc]; s += 32) {
                        int4   bo = *(const int4*)  &smp[s * 8];
                        float4 wv = *(const float4*)&smp[s * 8 + 4];
                        acc8(a[sc], fmT, bo.x, c8, wv.x);
                        acc8(a[sc], fmT, bo.y, c8, wv.y);
                        acc8(a[sc], fmT, bo.z, c8, wv.z);
                        acc8(a[sc], fmT, bo.w, c8, wv.w);
                    }
                }
                #pragma unroll
                for (int sc = 0; sc < 3; ++sc)
                    #pragma unroll
                    for (int i = 0; i < 8; ++i)
                        part[sc * 2112 + (c8 + i) * 33 + slot] = a[sc][i];
            }
            __syncthreads();
        }

        // ---------------- MLP (R6 micro-GEMM, LDS-resident inputs) ----------------
        float (*inp)[64]   = (float(*)[64])scr;             // 8192 B
        float (*h1)[132]   = (float(*)[132])(scr + 8192);   // 16896 B
        float (*catf)[256] = (float(*)[256])(scr + 25088);  // 8192 B
        float* big         = (float*)(scr + 33280);         // 16384 B (h2p / hidp / outp)

        #pragma unroll
        for (int it = 0; it < 8; ++it) {
            int idx = tid + it * 256;          // < 2048
            int m = idx >> 6, c = idx & 63;
            float v;
            if (m < 24) {
                int rb = m & 7, sc = m >> 3;
                v = (base + rb < n) ? pooled_s[rb][sc * 64 + c] : 0.0f;
            } else if (m == 24) v = g[c];
            else v = 0.0f;
            inp[m][c] = v;
        }
        __syncthreads();

        // ---- Stage 1: h1 = relu(inp @ W1 + b1) ----
        {
            int cg2 = tid & 31, rg = tid >> 5;
            int c4 = cg2 * 4, r4 = rg * 4;
            float acc[4][4] = {};
            for (int k = 0; k < 64; k += 4) {
                float4 a[4];
                #pragma unroll
                for (int rr = 0; rr < 4; ++rr) a[rr] = *(const float4*)&inp[r4 + rr][k];
                #pragma unroll
                for (int kk = 0; kk < 4; ++kk) {
                    float4 w = *(const float4*)&W1[(k + kk) * 128 + c4];
                    #pragma unroll
                    for (int rr = 0; rr < 4; ++rr) {
                        float av = ((const float*)&a[rr])[kk];
                        acc[rr][0] = fmaf(av, w.x, acc[rr][0]);
                        acc[rr][1] = fmaf(av, w.y, acc[rr][1]);
                        acc[rr][2] = fmaf(av, w.z, acc[rr][2]);
                        acc[rr][3] = fmaf(av, w.w, acc[rr][3]);
                    }
                }
            }
            float4 bb = *(const float4*)&b1[c4];
            #pragma unroll
            for (int rr = 0; rr < 4; ++rr) {
                float4 o;
                o.x = fmaxf(acc[rr][0] + bb.x, 0.0f);
                o.y = fmaxf(acc[rr][1] + bb.y, 0.0f);
                o.z = fmaxf(acc[rr][2] + bb.z, 0.0f);
                o.w = fmaxf(acc[rr][3] + bb.w, 0.0f);
                *(float4*)&h1[r4 + rr][c4] = o;
            }
        }
        __syncthreads();

        // ---- Stage 2: h2p[kg] = h1 @ W2 partials (K split 2) ----
        {
            int cg2 = tid & 15, rg = (tid >> 4) & 7, kg = tid >> 7;
            int c4 = cg2 * 4, r4 = rg * 4, k0 = kg * 64;
            float acc[4][4] = {};
            for (int k = k0; k < k0 + 64; k += 4) {
                float4 a[4];
                #pragma unroll
                for (int rr = 0; rr < 4; ++rr) a[rr] = *(const float4*)&h1[r4 + rr][k];
                #pragma unroll
                for (int kk = 0; kk < 4; ++kk) {
                    float4 w = *(const float4*)&W2[(k + kk) * 64 + c4];
                    #pragma unroll
                    for (int rr = 0; rr < 4; ++rr) {
                        float av = ((const float*)&a[rr])[kk];
                        acc[rr][0] = fmaf(av, w.x, acc[rr][0]);
                        acc[rr][1] = fmaf(av, w.y, acc[rr][1]);
                        acc[rr][2] = fmaf(av, w.z, acc[rr][2]);
                        acc[rr][3] = fmaf(av, w.w, acc[rr][3]);
                    }
                }
            }
            #pragma unroll
            for (int rr = 0; rr < 4; ++rr)
                *(float4*)&big[(kg * 32 + r4 + rr) * 64 + c4] =
                    make_float4(acc[rr][0], acc[rr][1], acc[rr][2], acc[rr][3]);
        }
        __syncthreads();
        #pragma unroll
        for (int it = 0; it < 8; ++it) {
            int idx = tid + it * 256;          // < 2048
            int r = idx >> 6, c = idx & 63;
            float v = fmaxf(big[r * 64 + c] + big[(32 + r) * 64 + c] + b2[c], 0.0f);
            if (r < 24) {
                catf[r & 7][(r >> 3) * 64 + c] = v;
            } else if (r == 24) {
                #pragma unroll
                for (int rr = 0; rr < 8; ++rr) catf[rr][192 + c] = v;
            }
        }
        __syncthreads();

        // ---- Stage 3: hidp[kg] = catf @ P1 partials (K split 4) ----
        {
            int cg2 = tid & 31, rg = (tid >> 5) & 1, kg = tid >> 6;
            int c4 = cg2 * 4, r4 = rg * 4, k0 = kg * 64;
            float acc[4][4] = {};
            for (int k = k0; k < k0 + 64; k += 4) {
                float4 a[4];
                #pragma unroll
                for (int rr = 0; rr < 4; ++rr) a[rr] = *(const float4*)&catf[r4 + rr][k];
                #pragma unroll
                for (int kk = 0; kk < 4; ++kk) {
                    float4 w = *(const float4*)&P1[(k + kk) * 128 + c4];
                    #pragma unroll
                    for (int rr = 0; rr < 4; ++rr) {
                        float av = ((const float*)&a[rr])[kk];
                        acc[rr][0] = fmaf(av, w.x, acc[rr][0]);
                        acc[rr][1] = fmaf(av, w.y, acc[rr][1]);
                        acc[rr][2] = fmaf(av, w.z, acc[rr][2]);
                        acc[rr][3] = fmaf(av, w.w, acc[rr][3]);
                    }
                }
            }
            #pragma unroll
            for (int rr = 0; rr < 4; ++rr)
                *(float4*)&big[(kg * 8 + r4 + rr) * 128 + c4] =
                    make_float4(acc[rr][0], acc[rr][1], acc[rr][2], acc[rr][3]);
        }
        __syncthreads();
        #pragma unroll
        for (int it = 0; it < 4; ++it) {
            int idx = tid + it * 256;          // < 1024
            int r = idx >> 7, j = idx & 127;
            h1[r][j] = fmaxf(big[r * 128 + j] + big[(8 + r) * 128 + j] +
                             big[(16 + r) * 128 + j] + big[(24 + r) * 128 + j] + bp1[j], 0.0f);
        }
        __syncthreads();

        // ---- Stage 4: outp[kg] = hid @ P2 partials (K split 4, 128 threads) ----
        if (tid < 128) {
            int cg2 = tid & 15, rg = (tid >> 4) & 1, kg = tid >> 5;
            int c4 = cg2 * 4, r4 = rg * 4, k0 = kg * 32;
            float acc[4][4] = {};
            for (int k = k0; k < k0 + 32; k += 4) {
                float4 a[4];
                #pragma unroll
                for (int rr = 0; rr < 4; ++rr) a[rr] = *(const float4*)&h1[r4 + rr][k];
                #pragma unroll
                for (int kk = 0; kk < 4; ++kk) {
                    float4 w = *(const float4*)&P2[(k + kk) * 64 + c4];
                    #pragma unroll
                    for (int rr = 0; rr < 4; ++rr) {
                        float av = ((const float*)&a[rr])[kk];
                        acc[rr][0] = fmaf(av, w.x, acc[rr][0]);
                        acc[rr][1] = fmaf(av, w.y, acc[rr][1]);
                        acc[rr][2] = fmaf(av, w.z, acc[rr][2]);
                        acc[rr][3] = fmaf(av, w.w, acc[rr][3]);
                    }
                }
            }
            #pragma unroll
            for (int rr = 0; rr < 4; ++rr)
                *(float4*)&big[(kg * 8 + r4 + rr) * 64 + c4] =
                    make_float4(acc[rr][0], acc[rr][1], acc[rr][2], acc[rr][3]);
        }
        __syncthreads();
        #pragma unroll
        for (int it = 0; it < 2; ++it) {
            int idx = tid + it * 256;          // < 512
            int r = idx >> 6, c = idx & 63;
            if (base + r < n) {
                float v = fmaxf(big[r * 64 + c] + big[(8 + r) * 64 + c] +
                                big[(16 + r) * 64 + c] + big[(24 + r) * 64 + c] + bp2[c], 0.0f);
                out[(size_t)perm[base + r] * 64 + c] = v;
            }
        }
        __syncthreads();   // scr reuse barrier before next group
    }
}

extern "C" void kernel_launch(void* const* d_in, const int* in_sizes, int n_in,
                              void* d_out, int out_size, void* d_ws, size_t ws_size,
                              hipStream_t stream) {
    const float* fm    = (const float*)d_in[0];
    const float* boxes = (const float*)d_in[1];
    const float* W1    = (const float*)d_in[2];
    const float* b1    = (const float*)d_in[3];
    const float* W2    = (const float*)d_in[4];
    const float* b2    = (const float*)d_in[5];
    const float* P1    = (const float*)d_in[6];
    const float* bp1   = (const float*)d_in[7];
    const float* P2    = (const float*)d_in[8];
    const float* bp2   = (const float*)d_in[9];
    float* ws = (float*)d_ws;
    __half* fmT     = (__half*)(ws + WS_FMT);
    float* gpartial = ws + WS_GPART;
    float* g        = ws + WS_G;
    int*   perm     = (int*)(ws + WS_PERM);
    float* out = (float*)d_out;
    int n = in_sizes[1] / 4;   // 4000 boxes

    int maxb = 0;
    hipOccupancyMaxActiveBlocksPerMultiprocessor(&maxb, k_fused, 256, 0);
    if (maxb < 1) maxb = 1;
    int grid = maxb * 256;     // 256 CUs; co-resident guarantee
    if (grid > 512) grid = 512;

    void* params[] = { (void*)&fm, (void*)&fmT, (void*)&gpartial, (void*)&g,
                       (void*)&boxes, (void*)&perm,
                       (void*)&W1, (void*)&b1, (void*)&W2, (void*)&b2,
                       (void*)&P1, (void*)&bp1, (void*)&P2, (void*)&bp2,
                       (void*)&out, (void*)&n };
    hipLaunchCooperativeKernel((const void*)k_fused, dim3(grid), dim3(256),
                               params, 0, stream);
}

// Round 9
// 229.452 us; speedup vs baseline: 2.4238x; 2.4238x over previous
//
#include <hip/hip_runtime.h>
#include <hip/hip_fp16.h>
#include <hip/hip_cooperative_groups.h>

namespace cg = cooperative_groups;

#define FH 240
#define FW 240
#define NSAMP 179   // 9 + 49 + 121
constexpr float IMG = 960.0f;

// ---------------- ws layout (floats) ----------------
static constexpr int WS_FMT   = 0;        // fmT fp16 [240][240][64] -> 1,843,200 float slots
static constexpr int WS_GPART = 1843200;  // gpartial [960][64]
static constexpr int WS_G     = 1904640;  // g [64] (pre-scaled by 1/57600)
static constexpr int WS_PERM  = 1904704;  // perm [4000] ints
static constexpr int WS_POOL  = 1908736;  // pooled [N][192]

// scratch: max(transpose tile 16640, sort 2048, pool smp+part 31104)
static constexpr int SCR_BYTES = 31104;

__device__ __forceinline__ void acc8(float* a, const __half* __restrict__ base,
                                     int off, int c8, float w) {
    float4 raw = *(const float4*)(base + off + c8);   // 8 fp16
    const __half2* h = (const __half2*)&raw;
    #pragma unroll
    for (int i = 0; i < 4; ++i) {
        float2 f = __half22float2(h[i]);
        a[2*i]     = fmaf(w, f.x, a[2*i]);
        a[2*i + 1] = fmaf(w, f.y, a[2*i + 1]);
    }
}

// ---------- Kernel 1 (cooperative): transpose + sort  ||grid.sync||  g-reduce + pool ----------
__global__ __launch_bounds__(256) void k_prep_pool(
    const float* __restrict__ fm, __half* __restrict__ fmT,
    float* __restrict__ gpartial, float* __restrict__ g,
    const float* __restrict__ boxes, int* __restrict__ perm,
    float* __restrict__ pooled, int n)
{
    __shared__ __align__(16) char scr[SCR_BYTES];
    int tid = threadIdx.x;
    int bid = blockIdx.x;
    int nblk = gridDim.x;
    cg::grid_group gg = cg::this_grid();

    // ===== Phase A: transpose fm -> fp16 fmT + per-tile channel sums (grid-stride) =====
    {
        float (*tile)[65] = (float(*)[65])scr;
        for (int t = bid; t < 960; t += nblk) {
            int y = t >> 2, x0 = (t & 3) * 64;
            int lane = tid & 63, wv = tid >> 6;
            int x = x0 + lane;
            bool xin = (x < FW);
            #pragma unroll
            for (int k = 0; k < 16; ++k) {
                int c = wv + k * 4;
                tile[c][lane] = xin ? fm[c * (FH * FW) + y * FW + x] : 0.0f;
            }
            __syncthreads();
            if (tid < 64) {
                float s = 0.0f;
                #pragma unroll
                for (int i = 0; i < 64; ++i) s += tile[tid][i];
                gpartial[t * 64 + tid] = s;
            }
            #pragma unroll
            for (int it = 0; it < 2; ++it) {
                int idx = tid + it * 256;       // 0..511
                int xl  = idx >> 3;             // 0..63
                int co  = (idx & 7) * 8;        // 0,8,...,56
                int xx  = x0 + xl;
                if (xx < FW) {
                    union { float4 f4; __half2 h2[4]; } u;
                    #pragma unroll
                    for (int i = 0; i < 4; ++i)
                        u.h2[i] = __floats2half2_rn(tile[co + 2*i][xl], tile[co + 2*i + 1][xl]);
                    *(float4*)&fmT[((size_t)(y * FW + xx)) * 64 + co] = u.f4;
                }
            }
            __syncthreads();
        }
    }
    // ---- counting sort of boxes by (cy,cx) 16x16 buckets: last block ----
    if (bid == nblk - 1) {
        int* hist = (int*)scr;
        int* offs = hist + 256;
        hist[tid] = 0;
        __syncthreads();
        for (int i = tid; i < n; i += 256) {
            float cy = (boxes[i * 4 + 1] + boxes[i * 4 + 3]) * 0.5f;
            float cx = (boxes[i * 4 + 0] + boxes[i * 4 + 2]) * 0.5f;
            int by = min(15, max(0, (int)(cy * (16.0f / 960.0f))));
            int bx = min(15, max(0, (int)(cx * (16.0f / 960.0f))));
            atomicAdd(&hist[by * 16 + bx], 1);
        }
        __syncthreads();
        offs[tid] = hist[tid];
        __syncthreads();
        for (int st = 1; st < 256; st <<= 1) {
            int t2 = (tid >= st) ? offs[tid - st] : 0;
            __syncthreads();
            offs[tid] += t2;
            __syncthreads();
        }
        hist[tid] = offs[tid] - hist[tid];     // exclusive start per bucket
        __syncthreads();
        for (int i = tid; i < n; i += 256) {
            float cy = (boxes[i * 4 + 1] + boxes[i * 4 + 3]) * 0.5f;
            float cx = (boxes[i * 4 + 0] + boxes[i * 4 + 2]) * 0.5f;
            int by = min(15, max(0, (int)(cy * (16.0f / 960.0f))));
            int bx = min(15, max(0, (int)(cx * (16.0f / 960.0f))));
            int pos = atomicAdd(&hist[by * 16 + bx], 1);
            perm[pos] = i;
        }
    }
    gg.sync();

    // ===== Phase B: block 0 reduces gpartial -> g =====
    if (bid == 0) {
        float* red = (float*)scr;
        int c = tid & 63, q = tid >> 6;
        float s = 0.0f;
        for (int i = q * 240; i < q * 240 + 240; ++i) s += gpartial[i * 64 + c];
        red[tid] = s;
        __syncthreads();
        if (tid < 64)
            g[tid] = (red[tid] + red[64 + tid] + red[128 + tid] + red[192 + tid]) * (1.0f / 57600.0f);
        __syncthreads();
    }

    // ===== Phase C: pool, one box per block-iteration (R6 structure, grid-stride) =====
    int* smp    = (int*)scr;                    // NSAMP*8 ints = 5728 B
    float* part = (float*)(scr + 5760);         // 3*2112 floats = 25344 B
    const int start_[3] = {0, 9, 58};
    const int end_[3]   = {9, 58, NSAMP};

    for (int p = bid; p < n; p += nblk) {
        int box = perm[p];

        if (tid < NSAMP) {
            float bx1 = boxes[box * 4 + 0], by1 = boxes[box * 4 + 1];
            float bx2 = boxes[box * 4 + 2], by2 = boxes[box * 4 + 3];
            float x1n = (bx1 / IMG) * 2.0f - 1.0f;
            float y1n = (by1 / IMG) * 2.0f - 1.0f;
            float x2n = (bx2 / IMG) * 2.0f - 1.0f;
            float y2n = (by2 / IMG) * 2.0f - 1.0f;
            float cx = (x1n + x2n) * 0.5f, cy = (y1n + y2n) * 0.5f;
            float w2 = fmaxf(x2n - x1n, 1e-6f) * 0.5f;
            float h2 = fmaxf(y2n - y1n, 1e-6f) * 0.5f;
            int S, s;
            if (tid < 9)       { S = 3;  s = tid; }
            else if (tid < 58) { S = 7;  s = tid - 9; }
            else               { S = 11; s = tid - 58; }
            int i = s / S;
            int j = s - i * S;
            float Sf = (float)S;
            float bj = (2.0f * (float)j + 1.0f) / Sf - 1.0f;
            float bi = (2.0f * (float)i + 1.0f) / Sf - 1.0f;
            float gx = w2 * bj + cx;
            float gy = h2 * bi + cy;
            float ix = ((gx + 1.0f) * 240.0f - 1.0f) * 0.5f;
            float iy = ((gy + 1.0f) * 240.0f - 1.0f) * 0.5f;
            float x0f = floorf(ix), y0f = floorf(iy);
            float dx = ix - x0f,    dy = iy - y0f;
            int x0 = (int)x0f, y0 = (int)y0f;
            int x1 = x0 + 1,   y1 = y0 + 1;
            float inv = 1.0f / (Sf * Sf);
            float wx0 = (x0 >= 0 && x0 < FW) ? (1.0f - dx) : 0.0f;
            float wx1 = (x1 >= 0 && x1 < FW) ? dx          : 0.0f;
            float wy0 = (y0 >= 0 && y0 < FH) ? (1.0f - dy) : 0.0f;
            float wy1 = (y1 >= 0 && y1 < FH) ? dy          : 0.0f;
            int x0c = min(max(x0, 0), FW - 1), x1c = min(max(x1, 0), FW - 1);
            int y0c = min(max(y0, 0), FH - 1), y1c = min(max(y1, 0), FH - 1);
            int r0 = y0c * FW, r1 = y1c * FW;
            smp[tid * 8 + 0] = (r0 + x0c) * 64;
            smp[tid * 8 + 1] = (r0 + x1c) * 64;
            smp[tid * 8 + 2] = (r1 + x0c) * 64;
            smp[tid * 8 + 3] = (r1 + x1c) * 64;
            float* wp = (float*)&smp[tid * 8 + 4];
            wp[0] = wx0 * wy0 * inv;
            wp[1] = wx1 * wy0 * inv;
            wp[2] = wx0 * wy1 * inv;
            wp[3] = wx1 * wy1 * inv;
        }
        __syncthreads();

        int slot = tid >> 3, l = tid & 7, c8 = l << 3;
        float a[3][8];
        #pragma unroll
        for (int sc = 0; sc < 3; ++sc)
            #pragma unroll
            for (int k = 0; k < 8; ++k) a[sc][k] = 0.0f;
        #pragma unroll
        for (int sc = 0; sc < 3; ++sc) {
            for (int s = start_[sc] + slot; s < end_[sc]; s += 32) {
                int4   bo = *(const int4*)  &smp[s * 8];
                float4 wv = *(const float4*)&smp[s * 8 + 4];
                acc8(a[sc], fmT, bo.x, c8, wv.x);
                acc8(a[sc], fmT, bo.y, c8, wv.y);
                acc8(a[sc], fmT, bo.z, c8, wv.z);
                acc8(a[sc], fmT, bo.w, c8, wv.w);
            }
        }
        #pragma unroll
        for (int sc = 0; sc < 3; ++sc)
            #pragma unroll
            for (int i = 0; i < 8; ++i)
                part[sc * 2112 + (c8 + i) * 33 + slot] = a[sc][i];
        __syncthreads();

        if (tid < 192) {
            int sc = tid >> 6, c = tid & 63;
            float sum = 0.0f;
            #pragma unroll
            for (int q = 0; q < 32; ++q) sum += part[sc * 2112 + c * 33 + q];
            pooled[(size_t)box * 192 + tid] = sum;
        }
        __syncthreads();   // protect smp/part before next box
    }
}

// ---------- Kernel 2: heads + final MLP, 4x4 register-tiled micro-GEMM (R6-proven) ----------
__global__ __launch_bounds__(256) void k_mlp(const float* __restrict__ pooled,
                                             const float* __restrict__ g,
                                             const float* __restrict__ W1, const float* __restrict__ b1,
                                             const float* __restrict__ W2, const float* __restrict__ b2,
                                             const float* __restrict__ P1, const float* __restrict__ bp1,
                                             const float* __restrict__ P2, const float* __restrict__ bp2,
                                             float* __restrict__ out, int n) {
    __shared__ float inp[32][64];
    __shared__ float h1[32][132];
    __shared__ float h2p[2][32][64];
    __shared__ float catf[8][256];
    __shared__ float hidp[4][8][128];
    __shared__ float outp[4][8][64];
    int tid = threadIdx.x;
    int box0 = blockIdx.x * 8;

    #pragma unroll
    for (int it = 0; it < 6; ++it) {
        int idx = tid + it * 256;          // < 1536
        int m = idx >> 6, c = idx & 63;
        int rb = m & 7, sc = m >> 3;
        inp[m][c] = (box0 + rb < n) ? pooled[(size_t)(box0 + rb) * 192 + sc * 64 + c] : 0.0f;
    }
    #pragma unroll
    for (int it = 0; it < 2; ++it) {
        int idx = tid + it * 256;          // < 512
        int m = 24 + (idx >> 6), c = idx & 63;
        inp[m][c] = (m == 24) ? g[c] : 0.0f;
    }
    __syncthreads();

    // ---- Stage 1: h1 = relu(inp @ W1 + b1) ----
    {
        int cg2 = tid & 31, rg = tid >> 5;
        int c4 = cg2 * 4, r4 = rg * 4;
        float acc[4][4] = {};
        for (int k = 0; k < 64; k += 4) {
            float4 a[4];
            #pragma unroll
            for (int rr = 0; rr < 4; ++rr) a[rr] = *(const float4*)&inp[r4 + rr][k];
            #pragma unroll
            for (int kk = 0; kk < 4; ++kk) {
                float4 w = *(const float4*)&W1[(k + kk) * 128 + c4];
                #pragma unroll
                for (int rr = 0; rr < 4; ++rr) {
                    float av = ((const float*)&a[rr])[kk];
                    acc[rr][0] = fmaf(av, w.x, acc[rr][0]);
                    acc[rr][1] = fmaf(av, w.y, acc[rr][1]);
                    acc[rr][2] = fmaf(av, w.z, acc[rr][2]);
                    acc[rr][3] = fmaf(av, w.w, acc[rr][3]);
                }
            }
        }
        float4 bb = *(const float4*)&b1[c4];
        #pragma unroll
        for (int rr = 0; rr < 4; ++rr) {
            float4 o;
            o.x = fmaxf(acc[rr][0] + bb.x, 0.0f);
            o.y = fmaxf(acc[rr][1] + bb.y, 0.0f);
            o.z = fmaxf(acc[rr][2] + bb.z, 0.0f);
            o.w = fmaxf(acc[rr][3] + bb.w, 0.0f);
            *(float4*)&h1[r4 + rr][c4] = o;
        }
    }
    __syncthreads();

    // ---- Stage 2: h2p[kg] = h1 @ W2 partials (K split 2) ----
    {
        int cg2 = tid & 15, rg = (tid >> 4) & 7, kg = tid >> 7;
        int c4 = cg2 * 4, r4 = rg * 4, k0 = kg * 64;
        float acc[4][4] = {};
        for (int k = k0; k < k0 + 64; k += 4) {
            float4 a[4];
            #pragma unroll
            for (int rr = 0; rr < 4; ++rr) a[rr] = *(const float4*)&h1[r4 + rr][k];
            #pragma unroll
            for (int kk = 0; kk < 4; ++kk) {
                float4 w = *(const float4*)&W2[(k + kk) * 64 + c4];
                #pragma unroll
                for (int rr = 0; rr < 4; ++rr) {
                    float av = ((const float*)&a[rr])[kk];
                    acc[rr][0] = fmaf(av, w.x, acc[rr][0]);
                    acc[rr][1] = fmaf(av, w.y, acc[rr][1]);
                    acc[rr][2] = fmaf(av, w.z, acc[rr][2]);
                    acc[rr][3] = fmaf(av, w.w, acc[rr][3]);
                }
            }
        }
        #pragma unroll
        for (int rr = 0; rr < 4; ++rr)
            *(float4*)&h2p[kg][r4 + rr][c4] = make_float4(acc[rr][0], acc[rr][1], acc[rr][2], acc[rr][3]);
    }
    __syncthreads();
    #pragma unroll
    for (int it = 0; it < 8; ++it) {
        int idx = tid + it * 256;          // < 2048
        int r = idx >> 6, c = idx & 63;
        float v = fmaxf(h2p[0][r][c] + h2p[1][r][c] + b2[c], 0.0f);
        if (r < 24) {
            catf[r & 7][(r >> 3) * 64 + c] = v;
        } else if (r == 24) {
            #pragma unroll
            for (int rr = 0; rr < 8; ++rr) catf[rr][192 + c] = v;
        }
    }
    __syncthreads();

    // ---- Stage 3: hidp[kg] = catf @ P1 partials (K split 4) ----
    {
        int cg2 = tid & 31, rg = (tid >> 5) & 1, kg = tid >> 6;
        int c4 = cg2 * 4, r4 = rg * 4, k0 = kg * 64;
        float acc[4][4] = {};
        for (int k = k0; k < k0 + 64; k += 4) {
            float4 a[4];
            #pragma unroll
            for (int rr = 0; rr < 4; ++rr) a[rr] = *(const float4*)&catf[r4 + rr][k];
            #pragma unroll
            for (int kk = 0; kk < 4; ++kk) {
                float4 w = *(const float4*)&P1[(k + kk) * 128 + c4];
                #pragma unroll
                for (int rr = 0; rr < 4; ++rr) {
                    float av = ((const float*)&a[rr])[kk];
                    acc[rr][0] = fmaf(av, w.x, acc[rr][0]);
                    acc[rr][1] = fmaf(av, w.y, acc[rr][1]);
                    acc[rr][2] = fmaf(av, w.z, acc[rr][2]);
                    acc[rr][3] = fmaf(av, w.w, acc[rr][3]);
                }
            }
        }
        #pragma unroll
        for (int rr = 0; rr < 4; ++rr)
            *(float4*)&hidp[kg][r4 + rr][c4] = make_float4(acc[rr][0], acc[rr][1], acc[rr][2], acc[rr][3]);
    }
    __syncthreads();
    #pragma unroll
    for (int it = 0; it < 4; ++it) {
        int idx = tid + it * 256;          // < 1024
        int r = idx >> 7, j = idx & 127;
        h1[r][j] = fmaxf(hidp[0][r][j] + hidp[1][r][j] + hidp[2][r][j] + hidp[3][r][j] + bp1[j], 0.0f);
    }
    __syncthreads();

    // ---- Stage 4: outp[kg] = hid @ P2 partials (K split 4, 128 threads) ----
    if (tid < 128) {
        int cg2 = tid & 15, rg = (tid >> 4) & 1, kg = tid >> 5;
        int c4 = cg2 * 4, r4 = rg * 4, k0 = kg * 32;
        float acc[4][4] = {};
        for (int k = k0; k < k0 + 32; k += 4) {
            float4 a[4];
            #pragma unroll
            for (int rr = 0; rr < 4; ++rr) a[rr] = *(const float4*)&h1[r4 + rr][k];
            #pragma unroll
            for (int kk = 0; kk < 4; ++kk) {
                float4 w = *(const float4*)&P2[(k + kk) * 64 + c4];
                #pragma unroll
                for (int rr = 0; rr < 4; ++rr) {
                    float av = ((const float*)&a[rr])[kk];
                    acc[rr][0] = fmaf(av, w.x, acc[rr][0]);
                    acc[rr][1] = fmaf(av, w.y, acc[rr][1]);
                    acc[rr][2] = fmaf(av, w.z, acc[rr][2]);
                    acc[rr][3] = fmaf(av, w.w, acc[rr][3]);
                }
            }
        }
        #pragma unroll
        for (int rr = 0; rr < 4; ++rr)
            *(float4*)&outp[kg][r4 + rr][c4] = make_float4(acc[rr][0], acc[rr][1], acc[rr][2], acc[rr][3]);
    }
    __syncthreads();
    #pragma unroll
    for (int it = 0; it < 2; ++it) {
        int idx = tid + it * 256;          // < 512
        int r = idx >> 6, c = idx & 63;
        int row = box0 + r;
        if (row < n) {
            float v = fmaxf(outp[0][r][c] + outp[1][r][c] + outp[2][r][c] + outp[3][r][c] + bp2[c], 0.0f);
            out[(size_t)row * 64 + c] = v;
        }
    }
}

extern "C" void kernel_launch(void* const* d_in, const int* in_sizes, int n_in,
                              void* d_out, int out_size, void* d_ws, size_t ws_size,
                              hipStream_t stream) {
    const float* fm    = (const float*)d_in[0];
    const float* boxes = (const float*)d_in[1];
    const float* W1    = (const float*)d_in[2];
    const float* b1    = (const float*)d_in[3];
    const float* W2    = (const float*)d_in[4];
    const float* b2    = (const float*)d_in[5];
    const float* P1    = (const float*)d_in[6];
    const float* bp1   = (const float*)d_in[7];
    const float* P2    = (const float*)d_in[8];
    const float* bp2   = (const float*)d_in[9];
    float* ws = (float*)d_ws;
    __half* fmT     = (__half*)(ws + WS_FMT);
    float* gpartial = ws + WS_GPART;
    float* g        = ws + WS_G;
    int*   perm     = (int*)(ws + WS_PERM);
    float* pooled   = ws + WS_POOL;
    float* out = (float*)d_out;
    int n = in_sizes[1] / 4;   // 4000 boxes

    int maxb = 0;
    hipOccupancyMaxActiveBlocksPerMultiprocessor(&maxb, k_prep_pool, 256, 0);
    if (maxb < 1) maxb = 1;
    long long grid = (long long)maxb * 256;
    if (grid > n) grid = n;

    void* params[] = { (void*)&fm, (void*)&fmT, (void*)&gpartial, (void*)&g,
                       (void*)&boxes, (void*)&perm, (void*)&pooled, (void*)&n };
    hipLaunchCooperativeKernel((const void*)k_prep_pool, dim3((int)grid), dim3(256),
                               params, 0, stream);
    k_mlp<<<(n + 7) / 8, 256, 0, stream>>>(pooled, g, W1, b1, W2, b2,
                                           P1, bp1, P2, bp2, out, n);
}

// Round 10
// 127.927 us; speedup vs baseline: 4.3474x; 1.7936x over previous
//
#include <hip/hip_runtime.h>
#include <hip/hip_fp16.h>

#define FH 240
#define FW 240
#define NSAMP 179   // 9 + 49 + 121
constexpr float IMG = 960.0f;

// ---------------- ws layout (floats) ----------------
static constexpr int WS_FMT   = 0;        // fmT fp16 [240][240][64] -> 1,843,200 float slots
static constexpr int WS_GPART = 1843200;  // gpartial [960][64]
static constexpr int WS_G     = 1904640;  // g [64] (pre-scaled by 1/57600)
static constexpr int WS_PERM  = 1904704;  // perm [4000] ints
static constexpr int WS_POOL  = 1908736;  // pooled [N][192]

// ---------- Kernel 1: blocks 0..959 transpose fm -> fp16 fmT + channel partials;
//                      block 960: counting-sort boxes by (cy,cx) buckets -> perm ----------
__global__ __launch_bounds__(256) void k_prep(const float* __restrict__ fm,
                                              __half* __restrict__ fmT,
                                              float* __restrict__ gpartial,
                                              const float* __restrict__ boxes,
                                              int* __restrict__ perm, int n) {
    __shared__ float tile[64][65];
    __shared__ int hist[256];
    __shared__ int offs[256];
    int bid = blockIdx.x;
    int tid = threadIdx.x;

    if (bid < 960) {
        int y  = bid >> 2;
        int x0 = (bid & 3) * 64;
        int lane = tid & 63;
        int wv   = tid >> 6;
        int x = x0 + lane;
        bool xin = (x < FW);
        #pragma unroll
        for (int k = 0; k < 16; ++k) {
            int c = wv + k * 4;
            tile[c][lane] = xin ? fm[c * (FH * FW) + y * FW + x] : 0.0f;
        }
        __syncthreads();

        if (tid < 64) {
            float s = 0.0f;
            #pragma unroll
            for (int i = 0; i < 64; ++i) s += tile[tid][i];
            gpartial[bid * 64 + tid] = s;
        }

        #pragma unroll
        for (int it = 0; it < 2; ++it) {
            int idx = tid + it * 256;       // 0..511
            int xl  = idx >> 3;             // 0..63
            int co  = (idx & 7) * 8;        // 0,8,...,56
            int xx  = x0 + xl;
            if (xx < FW) {
                union { float4 f4; __half2 h2[4]; } u;
                #pragma unroll
                for (int i = 0; i < 4; ++i)
                    u.h2[i] = __floats2half2_rn(tile[co + 2*i][xl], tile[co + 2*i + 1][xl]);
                *(float4*)&fmT[((size_t)(y * FW + xx)) * 64 + co] = u.f4;
            }
        }
    } else {
        // ---- counting sort of boxes by (cy, cx) 16x16 buckets ----
        hist[tid] = 0;
        __syncthreads();
        for (int i = tid; i < n; i += 256) {
            float cy = (boxes[i * 4 + 1] + boxes[i * 4 + 3]) * 0.5f;
            float cx = (boxes[i * 4 + 0] + boxes[i * 4 + 2]) * 0.5f;
            int by = min(15, max(0, (int)(cy * (16.0f / 960.0f))));
            int bx = min(15, max(0, (int)(cx * (16.0f / 960.0f))));
            atomicAdd(&hist[by * 16 + bx], 1);
        }
        __syncthreads();
        offs[tid] = hist[tid];
        __syncthreads();
        for (int st = 1; st < 256; st <<= 1) {
            int t2 = (tid >= st) ? offs[tid - st] : 0;
            __syncthreads();
            offs[tid] += t2;
            __syncthreads();
        }
        hist[tid] = offs[tid] - hist[tid];     // exclusive start per bucket
        __syncthreads();
        for (int i = tid; i < n; i += 256) {
            float cy = (boxes[i * 4 + 1] + boxes[i * 4 + 3]) * 0.5f;
            float cx = (boxes[i * 4 + 0] + boxes[i * 4 + 2]) * 0.5f;
            int by = min(15, max(0, (int)(cy * (16.0f / 960.0f))));
            int bx = min(15, max(0, (int)(cx * (16.0f / 960.0f))));
            int pos = atomicAdd(&hist[by * 16 + bx], 1);
            perm[pos] = i;
        }
    }
}

// ---------- Kernel 2: ROI bilinear pooling ----------
// One box per block (4000 short-lived blocks -> latency hidden by block turnover).
// LDS slimmed to ~14.2 KB (per-scale part buffer) -> 8 blocks/CU wave cap.
__device__ __forceinline__ void acc8(float* a, const __half* __restrict__ base,
                                     int off, int c8, float w) {
    float4 raw = *(const float4*)(base + off + c8);   // 8 fp16
    const __half2* h = (const __half2*)&raw;
    #pragma unroll
    for (int i = 0; i < 4; ++i) {
        float2 f = __half22float2(h[i]);
        a[2*i]     = fmaf(w, f.x, a[2*i]);
        a[2*i + 1] = fmaf(w, f.y, a[2*i + 1]);
    }
}

__global__ __launch_bounds__(256) void k_pool(const __half* __restrict__ fmT,
                                              const float* __restrict__ boxes,
                                              const int* __restrict__ perm,
                                              const float* __restrict__ gpartial,
                                              float* __restrict__ g,
                                              float* __restrict__ pooled) {
    __shared__ int   smp[NSAMP * 8];        // 5728 B
    __shared__ float part[64 * 33];         // 8448 B (one scale at a time)

    int tid = threadIdx.x;

    // block 0 extra duty: reduce gpartial -> g (pre-scaled)
    if (blockIdx.x == 0) {
        int c = tid & 63, q = tid >> 6;
        float s = 0.0f;
        for (int i = q * 240; i < q * 240 + 240; ++i) s += gpartial[i * 64 + c];
        part[tid] = s;
        __syncthreads();
        if (tid < 64)
            g[tid] = (part[tid] + part[64 + tid] + part[128 + tid] + part[192 + tid]) * (1.0f / 57600.0f);
        __syncthreads();
    }

    int box = perm[blockIdx.x];

    // --- Phase 1: one thread per sample ---
    if (tid < NSAMP) {
        float bx1 = boxes[box * 4 + 0], by1 = boxes[box * 4 + 1];
        float bx2 = boxes[box * 4 + 2], by2 = boxes[box * 4 + 3];
        float x1n = (bx1 / IMG) * 2.0f - 1.0f;
        float y1n = (by1 / IMG) * 2.0f - 1.0f;
        float x2n = (bx2 / IMG) * 2.0f - 1.0f;
        float y2n = (by2 / IMG) * 2.0f - 1.0f;
        float cx = (x1n + x2n) * 0.5f, cy = (y1n + y2n) * 0.5f;
        float w2 = fmaxf(x2n - x1n, 1e-6f) * 0.5f;
        float h2 = fmaxf(y2n - y1n, 1e-6f) * 0.5f;
        int S, s;
        if (tid < 9)       { S = 3;  s = tid; }
        else if (tid < 58) { S = 7;  s = tid - 9; }
        else               { S = 11; s = tid - 58; }
        int i = s / S;
        int j = s - i * S;
        float Sf = (float)S;
        float bj = (2.0f * (float)j + 1.0f) / Sf - 1.0f;
        float bi = (2.0f * (float)i + 1.0f) / Sf - 1.0f;
        float gx = w2 * bj + cx;
        float gy = h2 * bi + cy;
        float ix = ((gx + 1.0f) * 240.0f - 1.0f) * 0.5f;
        float iy = ((gy + 1.0f) * 240.0f - 1.0f) * 0.5f;
        float x0f = floorf(ix), y0f = floorf(iy);
        float dx = ix - x0f,    dy = iy - y0f;
        int x0 = (int)x0f, y0 = (int)y0f;
        int x1 = x0 + 1,   y1 = y0 + 1;
        float inv = 1.0f / (Sf * Sf);
        float wx0 = (x0 >= 0 && x0 < FW) ? (1.0f - dx) : 0.0f;
        float wx1 = (x1 >= 0 && x1 < FW) ? dx          : 0.0f;
        float wy0 = (y0 >= 0 && y0 < FH) ? (1.0f - dy) : 0.0f;
        float wy1 = (y1 >= 0 && y1 < FH) ? dy          : 0.0f;
        int x0c = min(max(x0, 0), FW - 1), x1c = min(max(x1, 0), FW - 1);
        int y0c = min(max(y0, 0), FH - 1), y1c = min(max(y1, 0), FH - 1);
        int r0 = y0c * FW, r1 = y1c * FW;
        smp[tid * 8 + 0] = (r0 + x0c) * 64;
        smp[tid * 8 + 1] = (r0 + x1c) * 64;
        smp[tid * 8 + 2] = (r1 + x0c) * 64;
        smp[tid * 8 + 3] = (r1 + x1c) * 64;
        float* wp = (float*)&smp[tid * 8 + 4];
        wp[0] = wx0 * wy0 * inv;
        wp[1] = wx1 * wy0 * inv;
        wp[2] = wx0 * wy1 * inv;
        wp[3] = wx1 * wy1 * inv;
    }
    __syncthreads();

    // --- Phase 2: per scale: gather (32 slots x 8 lanes, fp16 16-B loads) -> reduce ---
    int slot = tid >> 3, l = tid & 7, c8 = l << 3;
    const int start_[3] = {0, 9, 58};
    const int end_[3]   = {9, 58, NSAMP};

    #pragma unroll
    for (int sc = 0; sc < 3; ++sc) {
        float a[8];
        #pragma unroll
        for (int k = 0; k < 8; ++k) a[k] = 0.0f;
        for (int s = start_[sc] + slot; s < end_[sc]; s += 32) {
            int4   bo = *(const int4*)  &smp[s * 8];
            float4 wv = *(const float4*)&smp[s * 8 + 4];
            acc8(a, fmT, bo.x, c8, wv.x);
            acc8(a, fmT, bo.y, c8, wv.y);
            acc8(a, fmT, bo.z, c8, wv.z);
            acc8(a, fmT, bo.w, c8, wv.w);
        }
        #pragma unroll
        for (int i = 0; i < 8; ++i)
            part[(c8 + i) * 33 + slot] = a[i];
        __syncthreads();
        if (tid < 64) {
            float sum = 0.0f;
            #pragma unroll
            for (int q = 0; q < 32; ++q) sum += part[tid * 33 + q];
            pooled[(size_t)box * 192 + sc * 64 + tid] = sum;
        }
        __syncthreads();
    }
}

// ---------- Kernel 3: heads + final MLP, 4x4 register-tiled micro-GEMM (R6-proven) ----------
__global__ __launch_bounds__(256) void k_mlp(const float* __restrict__ pooled,
                                             const float* __restrict__ g,
                                             const float* __restrict__ W1, const float* __restrict__ b1,
                                             const float* __restrict__ W2, const float* __restrict__ b2,
                                             const float* __restrict__ P1, const float* __restrict__ bp1,
                                             const float* __restrict__ P2, const float* __restrict__ bp2,
                                             float* __restrict__ out, int n) {
    __shared__ float inp[32][64];
    __shared__ float h1[32][132];
    __shared__ float h2p[2][32][64];
    __shared__ float catf[8][256];
    __shared__ float hidp[4][8][128];
    __shared__ float outp[4][8][64];
    int tid = threadIdx.x;
    int box0 = blockIdx.x * 8;

    #pragma unroll
    for (int it = 0; it < 6; ++it) {
        int idx = tid + it * 256;          // < 1536
        int m = idx >> 6, c = idx & 63;
        int rb = m & 7, sc = m >> 3;
        inp[m][c] = (box0 + rb < n) ? pooled[(size_t)(box0 + rb) * 192 + sc * 64 + c] : 0.0f;
    }
    #pragma unroll
    for (int it = 0; it < 2; ++it) {
        int idx = tid + it * 256;          // < 512
        int m = 24 + (idx >> 6), c = idx & 63;
        inp[m][c] = (m == 24) ? g[c] : 0.0f;
    }
    __syncthreads();

    // ---- Stage 1: h1 = relu(inp @ W1 + b1) ----
    {
        int cg2 = tid & 31, rg = tid >> 5;
        int c4 = cg2 * 4, r4 = rg * 4;
        float acc[4][4] = {};
        for (int k = 0; k < 64; k += 4) {
            float4 a[4];
            #pragma unroll
            for (int rr = 0; rr < 4; ++rr) a[rr] = *(const float4*)&inp[r4 + rr][k];
            #pragma unroll
            for (int kk = 0; kk < 4; ++kk) {
                float4 w = *(const float4*)&W1[(k + kk) * 128 + c4];
                #pragma unroll
                for (int rr = 0; rr < 4; ++rr) {
                    float av = ((const float*)&a[rr])[kk];
                    acc[rr][0] = fmaf(av, w.x, acc[rr][0]);
                    acc[rr][1] = fmaf(av, w.y, acc[rr][1]);
                    acc[rr][2] = fmaf(av, w.z, acc[rr][2]);
                    acc[rr][3] = fmaf(av, w.w, acc[rr][3]);
                }
            }
        }
        float4 bb = *(const float4*)&b1[c4];
        #pragma unroll
        for (int rr = 0; rr < 4; ++rr) {
            float4 o;
            o.x = fmaxf(acc[rr][0] + bb.x, 0.0f);
            o.y = fmaxf(acc[rr][1] + bb.y, 0.0f);
            o.z = fmaxf(acc[rr][2] + bb.z, 0.0f);
            o.w = fmaxf(acc[rr][3] + bb.w, 0.0f);
            *(float4*)&h1[r4 + rr][c4] = o;
        }
    }
    __syncthreads();

    // ---- Stage 2: h2p[kg] = h1 @ W2 partials (K split 2) ----
    {
        int cg2 = tid & 15, rg = (tid >> 4) & 7, kg = tid >> 7;
        int c4 = cg2 * 4, r4 = rg * 4, k0 = kg * 64;
        float acc[4][4] = {};
        for (int k = k0; k < k0 + 64; k += 4) {
            float4 a[4];
            #pragma unroll
            for (int rr = 0; rr < 4; ++rr) a[rr] = *(const float4*)&h1[r4 + rr][k];
            #pragma unroll
            for (int kk = 0; kk < 4; ++kk) {
                float4 w = *(const float4*)&W2[(k + kk) * 64 + c4];
                #pragma unroll
                for (int rr = 0; rr < 4; ++rr) {
                    float av = ((const float*)&a[rr])[kk];
                    acc[rr][0] = fmaf(av, w.x, acc[rr][0]);
                    acc[rr][1] = fmaf(av, w.y, acc[rr][1]);
                    acc[rr][2] = fmaf(av, w.z, acc[rr][2]);
                    acc[rr][3] = fmaf(av, w.w, acc[rr][3]);
                }
            }
        }
        #pragma unroll
        for (int rr = 0; rr < 4; ++rr)
            *(float4*)&h2p[kg][r4 + rr][c4] = make_float4(acc[rr][0], acc[rr][1], acc[rr][2], acc[rr][3]);
    }
    __syncthreads();
    #pragma unroll
    for (int it = 0; it < 8; ++it) {
        int idx = tid + it * 256;          // < 2048
        int r = idx >> 6, c = idx & 63;
        float v = fmaxf(h2p[0][r][c] + h2p[1][r][c] + b2[c], 0.0f);
        if (r < 24) {
            catf[r & 7][(r >> 3) * 64 + c] = v;
        } else if (r == 24) {
            #pragma unroll
            for (int rr = 0; rr < 8; ++rr) catf[rr][192 + c] = v;
        }
    }
    __syncthreads();

    // ---- Stage 3: hidp[kg] = catf @ P1 partials (K split 4) ----
    {
        int cg2 = tid & 31, rg = (tid >> 5) & 1, kg = tid >> 6;
        int c4 = cg2 * 4, r4 = rg * 4, k0 = kg * 64;
        float acc[4][4] = {};
        for (int k = k0; k < k0 + 64; k += 4) {
            float4 a[4];
            #pragma unroll
            for (int rr = 0; rr < 4; ++rr) a[rr] = *(const float4*)&catf[r4 + rr][k];
            #pragma unroll
            for (int kk = 0; kk < 4; ++kk) {
                float4 w = *(const float4*)&P1[(k + kk) * 128 + c4];
                #pragma unroll
                for (int rr = 0; rr < 4; ++rr) {
                    float av = ((const float*)&a[rr])[kk];
                    acc[rr][0] = fmaf(av, w.x, acc[rr][0]);
                    acc[rr][1] = fmaf(av, w.y, acc[rr][1]);
                    acc[rr][2] = fmaf(av, w.z, acc[rr][2]);
                    acc[rr][3] = fmaf(av, w.w, acc[rr][3]);
                }
            }
        }
        #pragma unroll
        for (int rr = 0; rr < 4; ++rr)
            *(float4*)&hidp[kg][r4 + rr][c4] = make_float4(acc[rr][0], acc[rr][1], acc[rr][2], acc[rr][3]);
    }
    __syncthreads();
    #pragma unroll
    for (int it = 0; it < 4; ++it) {
        int idx = tid + it * 256;          // < 1024
        int r = idx >> 7, j = idx & 127;
        h1[r][j] = fmaxf(hidp[0][r][j] + hidp[1][r][j] + hidp[2][r][j] + hidp[3][r][j] + bp1[j], 0.0f);
    }
    __syncthreads();

    // ---- Stage 4: outp[kg] = hid @ P2 partials (K split 4, 128 threads) ----
    if (tid < 128) {
        int cg2 = tid & 15, rg = (tid >> 4) & 1, kg = tid >> 5;
        int c4 = cg2 * 4, r4 = rg * 4, k0 = kg * 32;
        float acc[4][4] = {};
        for (int k = k0; k < k0 + 32; k += 4) {
            float4 a[4];
            #pragma unroll
            for (int rr = 0; rr < 4; ++rr) a[rr] = *(const float4*)&h1[r4 + rr][k];
            #pragma unroll
            for (int kk = 0; kk < 4; ++kk) {
                float4 w = *(const float4*)&P2[(k + kk) * 64 + c4];
                #pragma unroll
                for (int rr = 0; rr < 4; ++rr) {
                    float av = ((const float*)&a[rr])[kk];
                    acc[rr][0] = fmaf(av, w.x, acc[rr][0]);
                    acc[rr][1] = fmaf(av, w.y, acc[rr][1]);
                    acc[rr][2] = fmaf(av, w.z, acc[rr][2]);
                    acc[rr][3] = fmaf(av, w.w, acc[rr][3]);
                }
            }
        }
        #pragma unroll
        for (int rr = 0; rr < 4; ++rr)
            *(float4*)&outp[kg][r4 + rr][c4] = make_float4(acc[rr][0], acc[rr][1], acc[rr][2], acc[rr][3]);
    }
    __syncthreads();
    #pragma unroll
    for (int it = 0; it < 2; ++it) {
        int idx = tid + it * 256;          // < 512
        int r = idx >> 6, c = idx & 63;
        int row = box0 + r;
        if (row < n) {
            float v = fmaxf(outp[0][r][c] + outp[1][r][c] + outp[2][r][c] + outp[3][r][c] + bp2[c], 0.0f);
            out[(size_t)row * 64 + c] = v;
        }
    }
}

extern "C" void kernel_launch(void* const* d_in, const int* in_sizes, int n_in,
                              void* d_out, int out_size, void* d_ws, size_t ws_size,
                              hipStream_t stream) {
    const float* fm    = (const float*)d_in[0];
    const float* boxes = (const float*)d_in[1];
    const float* W1    = (const float*)d_in[2];
    const float* b1    = (const float*)d_in[3];
    const float* W2    = (const float*)d_in[4];
    const float* b2    = (const float*)d_in[5];
    const float* P1    = (const float*)d_in[6];
    const float* bp1   = (const float*)d_in[7];
    const float* P2    = (const float*)d_in[8];
    const float* bp2   = (const float*)d_in[9];
    float* ws = (float*)d_ws;
    __half* fmT     = (__half*)(ws + WS_FMT);
    float* gpartial = ws + WS_GPART;
    float* g        = ws + WS_G;
    int*   perm     = (int*)(ws + WS_PERM);
    float* pooled   = ws + WS_POOL;
    float* out = (float*)d_out;
    int n = in_sizes[1] / 4;   // 4000 boxes

    k_prep<<<961, 256, 0, stream>>>(fm, fmT, gpartial, boxes, perm, n);
    k_pool<<<n, 256, 0, stream>>>(fmT, boxes, perm, gpartial, g, pooled);
    k_mlp<<<(n + 7) / 8, 256, 0, stream>>>(pooled, g, W1, b1, W2, b2,
                                           P1, bp1, P2, bp2, out, n);
}